// Round 1
// baseline (14998.859 us; speedup 1.0000x reference)
//
#include <hip/hip_runtime.h>

#define B_   64
#define T_   512
#define E_   256
#define H_   768
#define V_   5000
#define G4H  3072
#define BH   (B_ * H_)   // 49152

// ---------------------------------------------------------------------------
// bias_sum[i] = b_ih[i] + b_hh[i]
// ---------------------------------------------------------------------------
__global__ __launch_bounds__(256) void bias_sum_kernel(const float* __restrict__ b_ih,
                                                       const float* __restrict__ b_hh,
                                                       float* __restrict__ bias) {
  int i = blockIdx.x * 256 + threadIdx.x;
  if (i < G4H) bias[i] = b_ih[i] + b_hh[i];
}

// ---------------------------------------------------------------------------
// Generic tiled fp32 GEMM:  C[M][N] = Arows · Bm^T + bias
//   A is row-major [M][K] (MODE 0) or the houts buffer with row remap (MODE 1):
//     MODE 1: row r -> houts + ((r&511)+1)*BH + (r>>9)*H_   (r = b*512 + t)
//   Bm is row-major [N][K]  (so C[r][n] = dot(A[r], Bm[n]))
// Tile: BM=BN=128, BK=32, 256 threads, 8x8 per thread (split 4+4 for
// conflict-free LDS b128 reads: addresses tx*4 and 64+tx*4 -> 2-way = free).
// ---------------------------------------------------------------------------
template<int MODE>
__global__ __launch_bounds__(256) void gemm_nt(const float* __restrict__ A,
                                               const float* __restrict__ Bm,
                                               const float* __restrict__ bias,
                                               float* __restrict__ C,
                                               int M, int N, int K) {
  __shared__ float a_sh[32][132];
  __shared__ float b_sh[32][132];
  const int tid = threadIdx.x;
  const int tx = tid & 15;
  const int ty = tid >> 4;
  const int m0 = blockIdx.y * 128;
  const int n0 = blockIdx.x * 128;

  float acc[8][8];
#pragma unroll
  for (int i = 0; i < 8; i++)
#pragma unroll
    for (int j = 0; j < 8; j++) acc[i][j] = 0.f;

  for (int k0 = 0; k0 < K; k0 += 32) {
    __syncthreads();
    // ---- load A tile (128 x 32) as float4, 4 per thread ----
#pragma unroll
    for (int i = 0; i < 4; i++) {
      int idx = i * 256 + tid;
      int m = idx >> 3;
      int kv = (idx & 7) << 2;
      int r = m0 + m;
      float4 v = make_float4(0.f, 0.f, 0.f, 0.f);
      if (MODE == 1) {
        const float* p = A + (size_t)((r & 511) + 1) * BH + (size_t)(r >> 9) * H_ + k0 + kv;
        v = *(const float4*)p;
      } else {
        if (r < M) v = *(const float4*)(A + (size_t)r * K + k0 + kv);
      }
      a_sh[kv + 0][m] = v.x; a_sh[kv + 1][m] = v.y;
      a_sh[kv + 2][m] = v.z; a_sh[kv + 3][m] = v.w;
    }
    // ---- load B tile (128 x 32) ----
#pragma unroll
    for (int i = 0; i < 4; i++) {
      int idx = i * 256 + tid;
      int n = idx >> 3;
      int kv = (idx & 7) << 2;
      int r = n0 + n;
      float4 v = make_float4(0.f, 0.f, 0.f, 0.f);
      if (r < N) v = *(const float4*)(Bm + (size_t)r * K + k0 + kv);
      b_sh[kv + 0][n] = v.x; b_sh[kv + 1][n] = v.y;
      b_sh[kv + 2][n] = v.z; b_sh[kv + 3][n] = v.w;
    }
    __syncthreads();

#pragma unroll
    for (int kk = 0; kk < 32; kk++) {
      float4 a0 = *(const float4*)&a_sh[kk][ty * 4];
      float4 a1 = *(const float4*)&a_sh[kk][64 + ty * 4];
      float4 b0 = *(const float4*)&b_sh[kk][tx * 4];
      float4 b1 = *(const float4*)&b_sh[kk][64 + tx * 4];
      float av[8] = {a0.x, a0.y, a0.z, a0.w, a1.x, a1.y, a1.z, a1.w};
      float bv[8] = {b0.x, b0.y, b0.z, b0.w, b1.x, b1.y, b1.z, b1.w};
#pragma unroll
      for (int ri = 0; ri < 8; ri++)
#pragma unroll
        for (int ci = 0; ci < 8; ci++) acc[ri][ci] += av[ri] * bv[ci];
    }
  }

  // ---- epilogue ----
#pragma unroll
  for (int ri = 0; ri < 8; ri++) {
    int m = (ri < 4) ? (ty * 4 + ri) : (64 + ty * 4 + ri - 4);
    int r = m0 + m;
    if (r >= M) continue;
#pragma unroll
    for (int ci = 0; ci < 8; ci++) {
      int n = (ci < 4) ? (tx * 4 + ci) : (64 + tx * 4 + ci - 4);
      int col = n0 + n;
      if (col < N) C[(size_t)r * N + col] = acc[ri][ci] + bias[col];
    }
  }
}

// ---------------------------------------------------------------------------
// One LSTM time step.
// grid 192 blocks x 256 threads. Block = all 64 b x 4 j-columns.
// wave jl = tid>>6 owns column jcol = blockIdx.x*4 + jl; lane = batch b.
// gates[b][g*768+j] = eproj[x[b,t]][g*768+j] + dot(h_prev[b,:], W_hh[g*768+j,:])
// h tile XOR-swizzled in LDS (conflict-free b128 reads across lanes=b);
// W rows are wave-uniform -> broadcast LDS reads (conflict-free).
// c state stored [H][B] (lane-coalesced). houts stored [T+1][B][H].
// ---------------------------------------------------------------------------
__global__ __launch_bounds__(256) void lstm_step(const float* __restrict__ h_prev,
                                                 float* __restrict__ h_out,
                                                 float* __restrict__ c_st,
                                                 const float* __restrict__ eproj,
                                                 const int* __restrict__ x,
                                                 const float* __restrict__ W_hh,
                                                 int t) {
  __shared__ float h_lds[64][128];
  __shared__ float w_lds[16][128];
  const int tid = threadIdx.x;
  const int jl = tid >> 6;        // 0..3 : wave index = local column
  const int b  = tid & 63;        // lane = batch row
  const int jbase = blockIdx.x * 4;
  const int jcol = jbase + jl;    // 0..767

  const int idx_b = x[b * T_ + t];
  const float* ep = eproj + (size_t)idx_b * G4H + jcol;
  float acc0 = ep[0];
  float acc1 = ep[H_];
  float acc2 = ep[2 * H_];
  float acc3 = ep[3 * H_];

  for (int k0 = 0; k0 < H_; k0 += 128) {
    __syncthreads();
    // stage h tile: 64 b x 128 k, float4 loads, XOR-swizzle quad index by (b&7)
#pragma unroll
    for (int i = 0; i < 8; i++) {
      int idx = i * 256 + tid;
      int bb = idx >> 5;
      int q  = idx & 31;
      float4 v = *(const float4*)(h_prev + (size_t)bb * H_ + k0 + (q << 2));
      *(float4*)&h_lds[bb][(q ^ (bb & 7)) << 2] = v;
    }
    // stage W tile: 16 rows (4 gates x 4 local cols) x 128 k
#pragma unroll
    for (int i = 0; i < 2; i++) {
      int idx = i * 256 + tid;
      int r  = idx >> 5;                    // 0..15 : r = g*4 + jli
      int kv = (idx & 31) << 2;
      int row_g = (r >> 2) * H_ + jbase + (r & 3);
      *(float4*)&w_lds[r][kv] =
          *(const float4*)(W_hh + (size_t)row_g * H_ + k0 + kv);
    }
    __syncthreads();

#pragma unroll 4
    for (int q = 0; q < 32; q++) {
      float4 hv = *(const float4*)&h_lds[b][(q ^ (b & 7)) << 2];
      float4 w0 = *(const float4*)&w_lds[jl][q << 2];
      float4 w1 = *(const float4*)&w_lds[4 + jl][q << 2];
      float4 w2 = *(const float4*)&w_lds[8 + jl][q << 2];
      float4 w3 = *(const float4*)&w_lds[12 + jl][q << 2];
      acc0 += hv.x * w0.x + hv.y * w0.y + hv.z * w0.z + hv.w * w0.w;
      acc1 += hv.x * w1.x + hv.y * w1.y + hv.z * w1.z + hv.w * w1.w;
      acc2 += hv.x * w2.x + hv.y * w2.y + hv.z * w2.z + hv.w * w2.w;
      acc3 += hv.x * w3.x + hv.y * w3.y + hv.z * w3.z + hv.w * w3.w;
    }
  }

  // gate order: i, f, g, o
  float ig = 1.f / (1.f + __expf(-acc0));
  float fg = 1.f / (1.f + __expf(-acc1));
  float gg = tanhf(acc2);
  float og = 1.f / (1.f + __expf(-acc3));
  float c_prev = c_st[jcol * B_ + b];
  float cn = fg * c_prev + ig * gg;
  float hn = og * tanhf(cn);
  c_st[jcol * B_ + b] = cn;
  h_out[(size_t)b * H_ + jcol] = hn;
}

// ---------------------------------------------------------------------------
extern "C" void kernel_launch(void* const* d_in, const int* in_sizes, int n_in,
                              void* d_out, int out_size, void* d_ws, size_t ws_size,
                              hipStream_t stream) {
  const int*   x     = (const int*)d_in[0];
  // d_in[1] = truncate_length : irrelevant in forward
  const float* embed = (const float*)d_in[2];
  const float* W_ih  = (const float*)d_in[3];
  const float* W_hh  = (const float*)d_in[4];
  const float* b_ih  = (const float*)d_in[5];
  const float* b_hh  = (const float*)d_in[6];
  const float* fc_w  = (const float*)d_in[7];
  const float* fc_b  = (const float*)d_in[8];
  float* out = (float*)d_out;

  // workspace layout (floats)
  float* ws = (float*)d_ws;
  const size_t EPROJ_F = (size_t)V_ * G4H;         // 15,360,000
  const size_t HOUT_F  = (size_t)(T_ + 1) * BH;    // 25,214,976
  const size_t C_F     = BH;                       //     49,152
  const size_t BIAS_F  = G4H;                      //      3,072
  float* eproj = ws;
  float* houts = eproj + EPROJ_F;
  float* c_st  = houts + HOUT_F;
  float* bias  = c_st + C_F;
  const size_t NEEDED = (EPROJ_F + HOUT_F + C_F + BIAS_F) * sizeof(float);
  if (ws_size < NEEDED) return;  // would fail validation loudly

  // h_{-1} = 0 (houts slot 0), c_{-1} = 0
  hipMemsetAsync(houts, 0, BH * sizeof(float), stream);
  hipMemsetAsync(c_st, 0, BH * sizeof(float), stream);

  // bias_sum = b_ih + b_hh
  bias_sum_kernel<<<(G4H + 255) / 256, 256, 0, stream>>>(b_ih, b_hh, bias);

  // eproj[v][:] = embed[v] @ W_ih^T + bias_sum      (M=5000, N=3072, K=256)
  gemm_nt<0><<<dim3(G4H / 128, (V_ + 127) / 128), 256, 0, stream>>>(
      embed, W_ih, bias, eproj, V_, G4H, E_);

  // sequential LSTM: step t reads houts[t], writes houts[t+1]
  for (int t = 0; t < T_; t++) {
    lstm_step<<<H_ / 4, 256, 0, stream>>>(houts + (size_t)t * BH,
                                          houts + (size_t)(t + 1) * BH,
                                          c_st, eproj, x, W_hh, t);
  }

  // out[b][t][:] = h_t[b] @ fc_w^T + fc_b           (M=32768, N=5000, K=768)
  gemm_nt<1><<<dim3((V_ + 127) / 128, (B_ * T_) / 128), 256, 0, stream>>>(
      houts, fc_w, fc_b, out, B_ * T_, V_, H_);
}